// Round 3
// baseline (203.940 us; speedup 1.0000x reference)
//
#include <hip/hip_runtime.h>
#include <hip/hip_bf16.h>

#define S_ 2048
#define D_ 512
#define HD_ 64
#define HH_ 8
#define M_ 8192

typedef __attribute__((ext_vector_type(8))) short short8;
typedef __attribute__((ext_vector_type(4))) short short4v;
typedef __attribute__((ext_vector_type(4))) float f32x4;

__device__ __forceinline__ unsigned short f2bf(float f) {
  unsigned u = __builtin_bit_cast(unsigned, f);
  u += 0x7fffu + ((u >> 16) & 1u);
  return (unsigned short)(u >> 16);
}

__device__ __forceinline__ f32x4 mfma16(short8 a, short8 b, f32x4 c) {
  return __builtin_amdgcn_mfma_f32_16x16x32_bf16(a, b, c, 0, 0, 0);
}

#define GLOAD_LDS16(gp, lp)                                                        \
  __builtin_amdgcn_global_load_lds(                                                \
      (const __attribute__((address_space(1))) void*)(gp),                         \
      (__attribute__((address_space(3))) void*)(lp), 16, 0, 0)

// ---------------- converts ----------------

__global__ __launch_bounds__(256) void k_cvt_bf16x8(const float* __restrict__ x,
                                                    short* __restrict__ o) {
  int idx = blockIdx.x * 256 + threadIdx.x;
  const float4* p = (const float4*)x;
  float4 a = p[idx * 2];
  float4 b = p[idx * 2 + 1];
  short8 v;
  v[0] = (short)f2bf(a.x); v[1] = (short)f2bf(a.y);
  v[2] = (short)f2bf(a.z); v[3] = (short)f2bf(a.w);
  v[4] = (short)f2bf(b.x); v[5] = (short)f2bf(b.y);
  v[6] = (short)f2bf(b.z); v[7] = (short)f2bf(b.w);
  *(short8*)&o[idx * 8] = v;
}

__global__ __launch_bounds__(256) void k_cvt_transpose(const float* __restrict__ w,
                                                       short* __restrict__ wt,
                                                       int C) {
  int idx = blockIdx.x * 256 + threadIdx.x;
  int k = idx & 511;
  int n = idx >> 9;
  if (n < C) wt[n * 512 + k] = (short)f2bf(w[k * C + n]);
}

// ---------------- GEMM (128x128 tile, BK=32, 4 waves) ----------------
// MODE 0: qkv epilogue; Q outputs pre-scaled by 0.125*log2(e). MODE 1: fp32+bias.
template <int MODE>
__global__ __launch_bounds__(256) void k_gemm(const short* __restrict__ A,
                                              const short* __restrict__ Bt,
                                              const float* __restrict__ bias,
                                              short* __restrict__ Qo,
                                              short* __restrict__ Ko,
                                              short* __restrict__ VTo,
                                              float* __restrict__ Fo) {
  __shared__ short As[4096];
  __shared__ short Bs[4096];
  const int tid = threadIdx.x;
  const int w = tid >> 6, l = tid & 63, g = l >> 4, c = l & 15;
  const int bm = blockIdx.x * 128, bn = blockIdx.y * 128;
  const int wm = (w >> 1) * 64, wn = (w & 1) * 64;
  const int ch = w * 64 + l;
  const int ar = ch >> 2;
  const int ac = (ch & 3) * 8;
  f32x4 acc[4][4] = {};
  const short* Ap = A + (bm + ar) * 512 + ac;
  const short* Ap2 = Ap + 64 * 512;
  const short* Bp = Bt + (bn + ar) * 512 + ac;
  const short* Bp2 = Bp + 64 * 512;
  short* AsW = &As[w * 512];
  short* BsW = &Bs[w * 512];

  for (int k0 = 0; k0 < 512; k0 += 32) {
    __syncthreads();
    GLOAD_LDS16(Ap + k0, AsW);
    GLOAD_LDS16(Ap2 + k0, AsW + 2048);
    GLOAD_LDS16(Bp + k0, BsW);
    GLOAD_LDS16(Bp2 + k0, BsW + 2048);
    __syncthreads();
    short8 af[4], bfr[4];
#pragma unroll
    for (int mt = 0; mt < 4; mt++)
      af[mt] = *(const short8*)&As[(wm + mt * 16 + c) * 32 + 8 * g];
#pragma unroll
    for (int nt = 0; nt < 4; nt++)
      bfr[nt] = *(const short8*)&Bs[(wn + nt * 16 + c) * 32 + 8 * g];
#pragma unroll
    for (int mt = 0; mt < 4; mt++)
#pragma unroll
      for (int nt = 0; nt < 4; nt++)
        acc[mt][nt] = mfma16(af[mt], bfr[nt], acc[mt][nt]);
  }

  if (MODE == 0) {
    const float QS = 0.125f * 1.4426950408889634f;
#pragma unroll
    for (int nt = 0; nt < 4; nt++) {
      int n = bn + wn + nt * 16 + c;
      float bv = bias[n];
      int h = n / 192;
      int t = n - h * 192;
      int type = t >> 6;
      int hd = t & 63;
      float sc = (type == 0) ? QS : 1.0f;
#pragma unroll
      for (int mt = 0; mt < 4; mt++) {
        int m0 = bm + wm + mt * 16 + 4 * g;
        int b = m0 >> 11, s0 = m0 & 2047;
        int bh = b * 8 + h;
        if (type == 2) {
          short4v pk;
#pragma unroll
          for (int r = 0; r < 4; r++) pk[r] = (short)f2bf(acc[mt][nt][r] + bv);
          *(short4v*)&VTo[(bh * 64 + hd) * 2048 + s0] = pk;
        } else {
          short* dst = (type == 0) ? Qo : Ko;
#pragma unroll
          for (int r = 0; r < 4; r++)
            dst[(bh * 2048 + s0 + r) * 64 + hd] = (short)f2bf((acc[mt][nt][r] + bv) * sc);
        }
      }
    }
  } else {
#pragma unroll
    for (int nt = 0; nt < 4; nt++) {
      int n = bn + wn + nt * 16 + c;
      float bv = bias[n];
#pragma unroll
      for (int mt = 0; mt < 4; mt++) {
        int m0 = bm + wm + mt * 16 + 4 * g;
#pragma unroll
        for (int r = 0; r < 4; r++) Fo[(m0 + r) * 512 + n] = acc[mt][nt][r] + bv;
      }
    }
  }
}

// ---------------- flash attention (fixed-max softmax) ----------------
// 1024 blocks (LPT: longest q first), 4 waves/block, 16 q-rows/wave.
// Q pre-scaled by 0.125*log2e in GEMM epilogue; p = exp2(s - 16), no online
// max, no rescale; single cross-lane sum reduce at the end.
__global__ __launch_bounds__(256, 4) void k_attn(const short* __restrict__ Q,
                                                 const short* __restrict__ K,
                                                 const short* __restrict__ VT,
                                                 short* __restrict__ ctx) {
  __shared__ short P[4][16][72];
  const int tid = threadIdx.x;
  const int w = tid >> 6, l = tid & 63, g = l >> 4, c = l & 15;
  const int bid = blockIdx.x;
  const int bh = bid & 31;
  const int qb = 31 - (bid >> 5);      // descending work: longest first
  const int grp = 4 * qb + w;          // 16-row q-group 0..127
  const int qbase = grp * 16;
  const short* Qb = Q + bh * S_ * HD_;
  const short* Kb = K + bh * S_ * HD_;
  const short* Vb = VT + bh * HD_ * S_;

  short8 qf0 = *(const short8*)&Qb[(qbase + c) * 64 + 8 * g];
  short8 qf1 = *(const short8*)&Qb[(qbase + c) * 64 + 8 * g + 32];

  f32x4 o[4];
  float psum[4];
#pragma unroll
  for (int nt = 0; nt < 4; nt++) o[nt] = f32x4{0.f, 0.f, 0.f, 0.f};
#pragma unroll
  for (int r = 0; r < 4; r++) psum[r] = 0.f;

  const int kv_end = qbase + 16;

  short8 kf[4][2];
#pragma unroll
  for (int nt = 0; nt < 4; nt++)
#pragma unroll
    for (int h = 0; h < 2; h++)
      kf[nt][h] = *(const short8*)&Kb[(nt * 16 + c) * 64 + 8 * g + 32 * h];

  for (int kv0 = 0; kv0 < kv_end; kv0 += 64) {
    // V for current tile — issued early, consumed after softmax
    short8 vv[2][4];
#pragma unroll
    for (int kvb = 0; kvb < 2; kvb++)
#pragma unroll
      for (int nt = 0; nt < 4; nt++)
        vv[kvb][nt] = *(const short8*)&Vb[(nt * 16 + c) * S_ + kv0 + kvb * 32 + 8 * g];

    // QK^T on prefetched K (Q carries the softmax scale already)
    f32x4 sa[4];
#pragma unroll
    for (int nt = 0; nt < 4; nt++) {
      sa[nt] = mfma16(qf0, kf[nt][0], f32x4{0.f, 0.f, 0.f, 0.f});
      sa[nt] = mfma16(qf1, kf[nt][1], sa[nt]);
    }

    // prefetch next K tile
    if (kv0 + 64 < kv_end) {
#pragma unroll
      for (int nt = 0; nt < 4; nt++)
#pragma unroll
        for (int h = 0; h < 2; h++)
          kf[nt][h] = *(const short8*)&Kb[(kv0 + 64 + nt * 16 + c) * 64 + 8 * g + 32 * h];
    }

    // causal mask only on the diagonal tile
    if (kv0 + 64 > qbase) {
#pragma unroll
      for (int nt = 0; nt < 4; nt++) {
        int kv = kv0 + nt * 16 + c;
#pragma unroll
        for (int r = 0; r < 4; r++) {
          int qrow = qbase + 4 * g + r;
          if (kv > qrow) sa[nt][r] = -1e30f;
        }
      }
    }

    // p = exp2(s - 16); accumulate per-lane partial row sums; pack to LDS
#pragma unroll
    for (int nt = 0; nt < 4; nt++)
#pragma unroll
      for (int r = 0; r < 4; r++) {
        float p = exp2f(sa[nt][r] - 16.f);
        psum[r] += p;
        *(__hip_bfloat16*)&P[w][4 * g + r][nt * 16 + c] = __float2bfloat16(p);
      }

#pragma unroll
    for (int kvb = 0; kvb < 2; kvb++) {
      short8 pa = *(const short8*)&P[w][c][kvb * 32 + 8 * g];
#pragma unroll
      for (int nt = 0; nt < 4; nt++) o[nt] = mfma16(pa, vv[kvb][nt], o[nt]);
    }
  }

  // one cross-lane row-sum reduce (over the 16 c-lanes within each g-group)
#pragma unroll
  for (int off = 1; off < 16; off <<= 1)
#pragma unroll
    for (int r = 0; r < 4; r++) psum[r] += __shfl_xor(psum[r], off, 64);

  const int bb = bh >> 3, h = bh & 7;
  float inv[4];
#pragma unroll
  for (int r = 0; r < 4; r++) inv[r] = 1.0f / psum[r];
#pragma unroll
  for (int nt = 0; nt < 4; nt++)
#pragma unroll
    for (int r = 0; r < 4; r++) {
      int srow = qbase + 4 * g + r;
      ctx[(bb * S_ + srow) * 512 + h * 64 + nt * 16 + c] =
          (short)f2bf(o[nt][r] * inv[r]);
    }
}

// ---------------- launcher ----------------

extern "C" void kernel_launch(void* const* d_in, const int* in_sizes, int n_in,
                              void* d_out, int out_size, void* d_ws, size_t ws_size,
                              hipStream_t stream) {
  const float* x = (const float*)d_in[0];
  const float* Wqkv = (const float*)d_in[2];
  const float* bqkv = (const float*)d_in[3];
  const float* Wo = (const float*)d_in[4];
  const float* bo = (const float*)d_in[5];
  float* out = (float*)d_out;

  char* ws = (char*)d_ws;
  short* xb    = (short*)(ws + 0);
  short* wqkvt = (short*)(ws + 8388608);
  short* wot   = (short*)(ws + 9961472);
  short* Qw    = (short*)(ws + 10485760);
  short* Kw    = (short*)(ws + 18874368);
  short* VTw   = (short*)(ws + 27262976);
  short* ctx   = (short*)(ws + 35651584);

  k_cvt_bf16x8<<<2048, 256, 0, stream>>>(x, xb);
  k_cvt_transpose<<<3072, 256, 0, stream>>>(Wqkv, wqkvt, 1536);
  k_cvt_transpose<<<1024, 256, 0, stream>>>(Wo, wot, 512);

  dim3 g1(64, 12);
  k_gemm<0><<<g1, 256, 0, stream>>>(xb, wqkvt, bqkv, Qw, Kw, VTw, nullptr);

  k_attn<<<1024, 256, 0, stream>>>(Qw, Kw, VTw, ctx);

  dim3 g3(64, 4);
  k_gemm<1><<<g3, 256, 0, stream>>>(ctx, wot, bo, nullptr, nullptr, nullptr, out);
}

// Round 4
// 118.841 us; speedup vs baseline: 1.7161x; 1.7161x over previous
//
#include <hip/hip_runtime.h>
#include <hip/hip_bf16.h>

#define S_ 2048
#define D_ 512
#define HD_ 64
#define HH_ 8
#define M_ 8192

typedef __attribute__((ext_vector_type(8))) short short8;
typedef __attribute__((ext_vector_type(4))) short short4v;
typedef __attribute__((ext_vector_type(4))) float f32x4;

__device__ __forceinline__ unsigned short f2bf(float f) {
  unsigned u = __builtin_bit_cast(unsigned, f);
  u += 0x7fffu + ((u >> 16) & 1u);
  return (unsigned short)(u >> 16);
}

__device__ __forceinline__ f32x4 mfma16(short8 a, short8 b, f32x4 c) {
  return __builtin_amdgcn_mfma_f32_16x16x32_bf16(a, b, c, 0, 0, 0);
}

#define GLOAD_LDS16(gp, lp)                                                        \
  __builtin_amdgcn_global_load_lds(                                                \
      (const __attribute__((address_space(1))) void*)(gp),                         \
      (__attribute__((address_space(3))) void*)(lp), 16, 0, 0)

// ---------------- converts ----------------

__global__ __launch_bounds__(256) void k_cvt_bf16x8(const float* __restrict__ x,
                                                    short* __restrict__ o) {
  int idx = blockIdx.x * 256 + threadIdx.x;
  const float4* p = (const float4*)x;
  float4 a = p[idx * 2];
  float4 b = p[idx * 2 + 1];
  short8 v;
  v[0] = (short)f2bf(a.x); v[1] = (short)f2bf(a.y);
  v[2] = (short)f2bf(a.z); v[3] = (short)f2bf(a.w);
  v[4] = (short)f2bf(b.x); v[5] = (short)f2bf(b.y);
  v[6] = (short)f2bf(b.z); v[7] = (short)f2bf(b.w);
  *(short8*)&o[idx * 8] = v;
}

__global__ __launch_bounds__(256) void k_cvt_transpose(const float* __restrict__ w,
                                                       short* __restrict__ wt,
                                                       int C) {
  int idx = blockIdx.x * 256 + threadIdx.x;
  int k = idx & 511;
  int n = idx >> 9;
  if (n < C) wt[n * 512 + k] = (short)f2bf(w[k * C + n]);
}

// ---------------- GEMM (128x128 tile, BK=32, 4 waves) ----------------
// MODE 0: qkv epilogue; Q pre-scaled by 0.125*log2e; K stored with 16B-chunk
// XOR swizzle (chunk' = chunk ^ (s&7)); V^T stored with column-chunk swizzle
// (chunk' = chunk ^ (hd&7) within each 64-col block). MODE 1: fp32 + bias.
template <int MODE>
__global__ __launch_bounds__(256) void k_gemm(const short* __restrict__ A,
                                              const short* __restrict__ Bt,
                                              const float* __restrict__ bias,
                                              short* __restrict__ Qo,
                                              short* __restrict__ Ko,
                                              short* __restrict__ VTo,
                                              float* __restrict__ Fo) {
  __shared__ short As[4096];
  __shared__ short Bs[4096];
  const int tid = threadIdx.x;
  const int w = tid >> 6, l = tid & 63, g = l >> 4, c = l & 15;
  const int bm = blockIdx.x * 128, bn = blockIdx.y * 128;
  const int wm = (w >> 1) * 64, wn = (w & 1) * 64;
  const int ch = w * 64 + l;
  const int ar = ch >> 2;
  const int ac = (ch & 3) * 8;
  f32x4 acc[4][4] = {};
  const short* Ap = A + (bm + ar) * 512 + ac;
  const short* Ap2 = Ap + 64 * 512;
  const short* Bp = Bt + (bn + ar) * 512 + ac;
  const short* Bp2 = Bp + 64 * 512;
  short* AsW = &As[w * 512];
  short* BsW = &Bs[w * 512];

  for (int k0 = 0; k0 < 512; k0 += 32) {
    __syncthreads();
    GLOAD_LDS16(Ap + k0, AsW);
    GLOAD_LDS16(Ap2 + k0, AsW + 2048);
    GLOAD_LDS16(Bp + k0, BsW);
    GLOAD_LDS16(Bp2 + k0, BsW + 2048);
    __syncthreads();
    short8 af[4], bfr[4];
#pragma unroll
    for (int mt = 0; mt < 4; mt++)
      af[mt] = *(const short8*)&As[(wm + mt * 16 + c) * 32 + 8 * g];
#pragma unroll
    for (int nt = 0; nt < 4; nt++)
      bfr[nt] = *(const short8*)&Bs[(wn + nt * 16 + c) * 32 + 8 * g];
#pragma unroll
    for (int mt = 0; mt < 4; mt++)
#pragma unroll
      for (int nt = 0; nt < 4; nt++)
        acc[mt][nt] = mfma16(af[mt], bfr[nt], acc[mt][nt]);
  }

  if (MODE == 0) {
    const float QS = 0.125f * 1.4426950408889634f;
#pragma unroll
    for (int nt = 0; nt < 4; nt++) {
      int n = bn + wn + nt * 16 + c;
      float bv = bias[n];
      int h = n / 192;
      int t = n - h * 192;
      int type = t >> 6;
      int hd = t & 63;
      float sc = (type == 0) ? QS : 1.0f;
#pragma unroll
      for (int mt = 0; mt < 4; mt++) {
        int m0 = bm + wm + mt * 16 + 4 * g;
        int b = m0 >> 11, s0 = m0 & 2047;
        int bh = b * 8 + h;
        if (type == 2) {
          // V^T with column-chunk swizzle: col' = base | ((chunk^hd&7)<<3) | (s&7)
          int sw = (s0 & ~63) | (((((s0 >> 3) & 7) ^ (hd & 7)) << 3)) | (s0 & 7);
          short4v pk;
#pragma unroll
          for (int r = 0; r < 4; r++) pk[r] = (short)f2bf(acc[mt][nt][r] + bv);
          *(short4v*)&VTo[(bh * 64 + hd) * 2048 + sw] = pk;
        } else if (type == 1) {
          // K with row-chunk swizzle: hd' = ((hd>>3)^(s&7))<<3 | (hd&7)
#pragma unroll
          for (int r = 0; r < 4; r++) {
            int s = s0 + r;
            int hds = ((((hd >> 3) ^ (s & 7)) << 3)) | (hd & 7);
            Ko[(bh * 2048 + s) * 64 + hds] = (short)f2bf(acc[mt][nt][r] + bv);
          }
        } else {
#pragma unroll
          for (int r = 0; r < 4; r++)
            Qo[(bh * 2048 + s0 + r) * 64 + hd] = (short)f2bf((acc[mt][nt][r] + bv) * sc);
        }
      }
    }
  } else {
#pragma unroll
    for (int nt = 0; nt < 4; nt++) {
      int n = bn + wn + nt * 16 + c;
      float bv = bias[n];
#pragma unroll
      for (int mt = 0; mt < 4; mt++) {
        int m0 = bm + wm + mt * 16 + 4 * g;
#pragma unroll
        for (int r = 0; r < 4; r++) Fo[(m0 + r) * 512 + n] = acc[mt][nt][r] + bv;
      }
    }
  }
}

// ---------------- flash attention (block-cooperative, LDS-staged) ----------------
// 512 blocks = 32 bh x 16 q-blocks(128 rows). 4 waves x 32 rows. KV tile 64,
// double-buffered LDS staging (issue-early, barrier-drained under compute).
// Fixed-max softmax: p = exp2(s - 16), Q pre-scaled. LPT: qi descending for
// bid<256, ascending after, so same-CU pairs (x, x+256) sum to constant work.
__global__ __launch_bounds__(256, 2) void k_attn(const short* __restrict__ Q,
                                                 const short* __restrict__ K,
                                                 const short* __restrict__ VT,
                                                 short* __restrict__ ctx) {
  __shared__ short Ks[2][4096];   // [64 kv][64 hd] swizzled
  __shared__ short Vs[2][4096];   // [64 hd][64 kv] swizzled
  __shared__ short P[4][2048];    // per-wave [32 q][64 kv] swizzled
  const int tid = threadIdx.x;
  const int w = tid >> 6, l = tid & 63, g = l >> 4, c = l & 15;

  const int x = blockIdx.x;
  const int bh = x & 31;
  const int k5 = (x >> 5) & 7;
  const int qi = (x >> 8) ? k5 : 15 - k5;
  const int qbase0 = qi * 128;
  const int qbase = qbase0 + w * 32;

  const short* Qb = Q + bh * S_ * HD_;
  const short* Kb = K + bh * S_ * HD_;
  const short* Vb = VT + bh * HD_ * S_;

  short8 qf[2][2];
#pragma unroll
  for (int mf = 0; mf < 2; mf++)
#pragma unroll
    for (int h = 0; h < 2; h++)
      qf[mf][h] = *(const short8*)&Qb[(qbase + mf * 16 + c) * 64 + 8 * g + 32 * h];

  f32x4 o[2][4];
  float psum[2][4];
#pragma unroll
  for (int mf = 0; mf < 2; mf++) {
#pragma unroll
    for (int nt = 0; nt < 4; nt++) o[mf][nt] = f32x4{0.f, 0.f, 0.f, 0.f};
#pragma unroll
    for (int r = 0; r < 4; r++) psum[mf][r] = 0.f;
  }

  const int ntiles = 2 * qi + 2;
  const int i0 = tid, i1 = tid + 256;
  const int kr0 = i0 >> 3, kc0 = (i0 & 7) * 8;
  const int kr1 = i1 >> 3, kc1 = (i1 & 7) * 8;
  short* KL0 = &Ks[0][w * 512];        // wave-uniform LDS bases
  short* KL1 = &Ks[0][2048 + w * 512];
  short* VL0 = &Vs[0][w * 512];
  short* VL1 = &Vs[0][2048 + w * 512];

#define STAGE(buf, kv0)                                                     \
  {                                                                         \
    GLOAD_LDS16(Kb + ((kv0) + kr0) * 64 + kc0, KL0 + (buf)*4096);           \
    GLOAD_LDS16(Kb + ((kv0) + kr1) * 64 + kc1, KL1 + (buf)*4096);           \
    GLOAD_LDS16(Vb + kr0 * 2048 + (kv0) + kc0, VL0 + (buf)*4096);           \
    GLOAD_LDS16(Vb + kr1 * 2048 + (kv0) + kc1, VL1 + (buf)*4096);           \
  }

  STAGE(0, 0);
  __syncthreads();

  int cur = 0;
  for (int it = 0; it < ntiles; ++it) {
    const int kv0 = it * 64;
    if (it + 1 < ntiles) STAGE(cur ^ 1, kv0 + 64);

    const short* Kt = &Ks[cur][0];
    const short* Vt = &Vs[cur][0];

    // QK^T from LDS (swizzle-read)
    f32x4 sa[2][4];
#pragma unroll
    for (int nt = 0; nt < 4; nt++) {
      short8 kf0 = *(const short8*)&Kt[((nt * 16 + c) << 6) + (((g) ^ (c & 7)) << 3)];
      short8 kf1 = *(const short8*)&Kt[((nt * 16 + c) << 6) + (((g + 4) ^ (c & 7)) << 3)];
#pragma unroll
      for (int mf = 0; mf < 2; mf++) {
        sa[mf][nt] = mfma16(qf[mf][0], kf0, f32x4{0.f, 0.f, 0.f, 0.f});
        sa[mf][nt] = mfma16(qf[mf][1], kf1, sa[mf][nt]);
      }
    }

    // causal mask (only tiles overlapping/beyond this wave's rows)
    if (kv0 + 64 > qbase) {
#pragma unroll
      for (int nt = 0; nt < 4; nt++) {
        int kv = kv0 + nt * 16 + c;
#pragma unroll
        for (int mf = 0; mf < 2; mf++)
#pragma unroll
          for (int r = 0; r < 4; r++) {
            int qrow = qbase + mf * 16 + 4 * g + r;
            if (kv > qrow) sa[mf][nt][r] = -1e30f;
          }
      }
    }

    // p = exp2(s - 16); partial row sums; pack to swizzled P
#pragma unroll
    for (int mf = 0; mf < 2; mf++)
#pragma unroll
      for (int nt = 0; nt < 4; nt++)
#pragma unroll
        for (int r = 0; r < 4; r++) {
          float p = exp2f(sa[mf][nt][r] - 16.f);
          psum[mf][r] += p;
          int row = mf * 16 + 4 * g + r;
          int col = nt * 16 + c;
          int off = (row << 6) + ((((col >> 3) ^ (row & 7)) << 3)) + (col & 7);
          *(__hip_bfloat16*)&P[w][off] = __float2bfloat16(p);
        }

    // PV from LDS V (swizzle-read) and P (swizzle-read)
#pragma unroll
    for (int kvb = 0; kvb < 2; kvb++) {
      short8 pa[2];
#pragma unroll
      for (int mf = 0; mf < 2; mf++) {
        int row = mf * 16 + c;
        pa[mf] = *(const short8*)&P[w][(row << 6) + (((kvb * 4 + g) ^ (row & 7)) << 3)];
      }
#pragma unroll
      for (int nt = 0; nt < 4; nt++) {
        short8 vb = *(const short8*)&Vt[((nt * 16 + c) << 6) +
                                        (((kvb * 4 + g) ^ (c & 7)) << 3)];
        o[0][nt] = mfma16(pa[0], vb, o[0][nt]);
        o[1][nt] = mfma16(pa[1], vb, o[1][nt]);
      }
    }

    __syncthreads();   // drains this iter's STAGE (vmcnt 0) + syncs buffers
    cur ^= 1;
  }

  // cross-lane row-sum reduce (16 c-lanes per g-group)
#pragma unroll
  for (int off = 1; off < 16; off <<= 1)
#pragma unroll
    for (int mf = 0; mf < 2; mf++)
#pragma unroll
      for (int r = 0; r < 4; r++) psum[mf][r] += __shfl_xor(psum[mf][r], off, 64);

  const int bb = bh >> 3, h = bh & 7;
#pragma unroll
  for (int mf = 0; mf < 2; mf++) {
    float inv[4];
#pragma unroll
    for (int r = 0; r < 4; r++) inv[r] = 1.0f / psum[mf][r];
#pragma unroll
    for (int nt = 0; nt < 4; nt++)
#pragma unroll
      for (int r = 0; r < 4; r++) {
        int srow = qbase + mf * 16 + 4 * g + r;
        ctx[(bb * S_ + srow) * 512 + h * 64 + nt * 16 + c] =
            (short)f2bf(o[mf][nt][r] * inv[r]);
      }
  }
#undef STAGE
}

// ---------------- launcher ----------------

extern "C" void kernel_launch(void* const* d_in, const int* in_sizes, int n_in,
                              void* d_out, int out_size, void* d_ws, size_t ws_size,
                              hipStream_t stream) {
  const float* x = (const float*)d_in[0];
  const float* Wqkv = (const float*)d_in[2];
  const float* bqkv = (const float*)d_in[3];
  const float* Wo = (const float*)d_in[4];
  const float* bo = (const float*)d_in[5];
  float* out = (float*)d_out;

  char* ws = (char*)d_ws;
  short* xb    = (short*)(ws + 0);
  short* wqkvt = (short*)(ws + 8388608);
  short* wot   = (short*)(ws + 9961472);
  short* Qw    = (short*)(ws + 10485760);
  short* Kw    = (short*)(ws + 18874368);
  short* VTw   = (short*)(ws + 27262976);
  short* ctx   = (short*)(ws + 35651584);

  k_cvt_bf16x8<<<2048, 256, 0, stream>>>(x, xb);
  k_cvt_transpose<<<3072, 256, 0, stream>>>(Wqkv, wqkvt, 1536);
  k_cvt_transpose<<<1024, 256, 0, stream>>>(Wo, wot, 512);

  dim3 g1(64, 12);
  k_gemm<0><<<g1, 256, 0, stream>>>(xb, wqkvt, bqkv, Qw, Kw, VTw, nullptr);

  k_attn<<<512, 256, 0, stream>>>(Qw, Kw, VTw, ctx);

  dim3 g3(64, 4);
  k_gemm<1><<<g3, 256, 0, stream>>>(ctx, wot, bo, nullptr, nullptr, nullptr, out);
}

// Round 6
// 105.214 us; speedup vs baseline: 1.9383x; 1.1295x over previous
//
#include <hip/hip_runtime.h>
#include <hip/hip_bf16.h>

#define S_ 2048
#define D_ 512
#define HD_ 64
#define HH_ 8
#define M_ 8192

typedef __attribute__((ext_vector_type(8))) short short8;
typedef __attribute__((ext_vector_type(4))) short short4v;
typedef __attribute__((ext_vector_type(4))) float f32x4;

__device__ __forceinline__ unsigned short f2bf(float f) {
  unsigned u = __builtin_bit_cast(unsigned, f);
  u += 0x7fffu + ((u >> 16) & 1u);
  return (unsigned short)(u >> 16);
}

__device__ __forceinline__ f32x4 mfma16(short8 a, short8 b, f32x4 c) {
  return __builtin_amdgcn_mfma_f32_16x16x32_bf16(a, b, c, 0, 0, 0);
}

#define GLOAD_LDS16(gp, lp)                                                        \
  __builtin_amdgcn_global_load_lds(                                                \
      (const __attribute__((address_space(1))) void*)(gp),                         \
      (__attribute__((address_space(3))) void*)(lp), 16, 0, 0)

// ---------------- converts ----------------

__global__ __launch_bounds__(256) void k_cvt_bf16x8(const float* __restrict__ x,
                                                    short* __restrict__ o) {
  int idx = blockIdx.x * 256 + threadIdx.x;
  const float4* p = (const float4*)x;
  float4 a = p[idx * 2];
  float4 b = p[idx * 2 + 1];
  short8 v;
  v[0] = (short)f2bf(a.x); v[1] = (short)f2bf(a.y);
  v[2] = (short)f2bf(a.z); v[3] = (short)f2bf(a.w);
  v[4] = (short)f2bf(b.x); v[5] = (short)f2bf(b.y);
  v[6] = (short)f2bf(b.z); v[7] = (short)f2bf(b.w);
  *(short8*)&o[idx * 8] = v;
}

__global__ __launch_bounds__(256) void k_cvt_transpose(const float* __restrict__ w,
                                                       short* __restrict__ wt,
                                                       int C) {
  int idx = blockIdx.x * 256 + threadIdx.x;
  int k = idx & 511;
  int n = idx >> 9;
  if (n < C) wt[n * 512 + k] = (short)f2bf(w[k * C + n]);
}

// ---------------- GEMM (128x128 tile, BK=32, 4 waves) ----------------
// MODE 0: qkv epilogue; Q pre-scaled by 0.125*log2e; K stored with 16B-chunk
// XOR swizzle (chunk' = chunk ^ (s&7)); V^T stored with column-chunk swizzle
// (chunk' = chunk ^ (hd&7) within each 64-col block). MODE 1: fp32 + bias.
template <int MODE>
__global__ __launch_bounds__(256) void k_gemm(const short* __restrict__ A,
                                              const short* __restrict__ Bt,
                                              const float* __restrict__ bias,
                                              short* __restrict__ Qo,
                                              short* __restrict__ Ko,
                                              short* __restrict__ VTo,
                                              float* __restrict__ Fo) {
  __shared__ short As[4096];
  __shared__ short Bs[4096];
  const int tid = threadIdx.x;
  const int w = tid >> 6, l = tid & 63, g = l >> 4, c = l & 15;
  const int bm = blockIdx.x * 128, bn = blockIdx.y * 128;
  const int wm = (w >> 1) * 64, wn = (w & 1) * 64;
  const int ch = w * 64 + l;
  const int ar = ch >> 2;
  const int ac = (ch & 3) * 8;
  f32x4 acc[4][4] = {};
  const short* Ap = A + (bm + ar) * 512 + ac;
  const short* Ap2 = Ap + 64 * 512;
  const short* Bp = Bt + (bn + ar) * 512 + ac;
  const short* Bp2 = Bp + 64 * 512;
  short* AsW = &As[w * 512];
  short* BsW = &Bs[w * 512];

  for (int k0 = 0; k0 < 512; k0 += 32) {
    __syncthreads();
    GLOAD_LDS16(Ap + k0, AsW);
    GLOAD_LDS16(Ap2 + k0, AsW + 2048);
    GLOAD_LDS16(Bp + k0, BsW);
    GLOAD_LDS16(Bp2 + k0, BsW + 2048);
    __syncthreads();
    short8 af[4], bfr[4];
#pragma unroll
    for (int mt = 0; mt < 4; mt++)
      af[mt] = *(const short8*)&As[(wm + mt * 16 + c) * 32 + 8 * g];
#pragma unroll
    for (int nt = 0; nt < 4; nt++)
      bfr[nt] = *(const short8*)&Bs[(wn + nt * 16 + c) * 32 + 8 * g];
#pragma unroll
    for (int mt = 0; mt < 4; mt++)
#pragma unroll
      for (int nt = 0; nt < 4; nt++)
        acc[mt][nt] = mfma16(af[mt], bfr[nt], acc[mt][nt]);
  }

  if (MODE == 0) {
    const float QS = 0.125f * 1.4426950408889634f;
#pragma unroll
    for (int nt = 0; nt < 4; nt++) {
      int n = bn + wn + nt * 16 + c;
      float bv = bias[n];
      int h = n / 192;
      int t = n - h * 192;
      int type = t >> 6;
      int hd = t & 63;
      float sc = (type == 0) ? QS : 1.0f;
#pragma unroll
      for (int mt = 0; mt < 4; mt++) {
        int m0 = bm + wm + mt * 16 + 4 * g;
        int b = m0 >> 11, s0 = m0 & 2047;
        int bh = b * 8 + h;
        if (type == 2) {
          int sw = (s0 & ~63) | (((((s0 >> 3) & 7) ^ (hd & 7)) << 3)) | (s0 & 7);
          short4v pk;
#pragma unroll
          for (int r = 0; r < 4; r++) pk[r] = (short)f2bf(acc[mt][nt][r] + bv);
          *(short4v*)&VTo[(bh * 64 + hd) * 2048 + sw] = pk;
        } else if (type == 1) {
#pragma unroll
          for (int r = 0; r < 4; r++) {
            int s = s0 + r;
            int hds = ((((hd >> 3) ^ (s & 7)) << 3)) | (hd & 7);
            Ko[(bh * 2048 + s) * 64 + hds] = (short)f2bf(acc[mt][nt][r] + bv);
          }
        } else {
#pragma unroll
          for (int r = 0; r < 4; r++)
            Qo[(bh * 2048 + s0 + r) * 64 + hd] = (short)f2bf((acc[mt][nt][r] + bv) * sc);
        }
      }
    }
  } else {
#pragma unroll
    for (int nt = 0; nt < 4; nt++) {
      int n = bn + wn + nt * 16 + c;
      float bv = bias[n];
#pragma unroll
      for (int mt = 0; mt < 4; mt++) {
        int m0 = bm + wm + mt * 16 + 4 * g;
#pragma unroll
        for (int r = 0; r < 4; r++) Fo[(m0 + r) * 512 + n] = acc[mt][nt][r] + bv;
      }
    }
  }
}

// ---------------- flash attention (uniform-work, LDS-staged) ----------------
// 512 blocks = 32 bh x 16 tasks. Task j handles TWO 64-row q-chunks (j, then
// 31-j) -> every block does exactly 33 kv-tiles. 4 waves x 16 q-rows. KV
// double-buffered LDS staging. Softmax: p = exp2(s - 16) with -16 folded into
// the MFMA C-init; exp2f + __float2bfloat16 (round-4-proven path).
__global__ __launch_bounds__(256, 2) void k_attn(const short* __restrict__ Q,
                                                 const short* __restrict__ K,
                                                 const short* __restrict__ VT,
                                                 short* __restrict__ ctx) {
  __shared__ short Ks[2][4096];   // [64 kv][64 hd] swizzled
  __shared__ short Vs[2][4096];   // [64 hd][64 kv] swizzled
  __shared__ short P[4][1024];    // per-wave [16 q][64 kv] swizzled
  const int tid = threadIdx.x;
  const int w = tid >> 6, l = tid & 63, g = l >> 4, c = l & 15;

  const int x = blockIdx.x;
  const int bh = x & 31;
  const int j = x >> 5;            // task 0..15

  const short* Qb = Q + bh * S_ * HD_;
  const short* Kb = K + bh * S_ * HD_;
  const short* Vb = VT + bh * HD_ * S_;

  const int i0 = tid, i1 = tid + 256;
  const int kr0 = i0 >> 3, kc0 = (i0 & 7) * 8;
  const int kr1 = i1 >> 3, kc1 = (i1 & 7) * 8;
  short* KL0 = &Ks[0][w * 512];
  short* KL1 = &Ks[0][2048 + w * 512];
  short* VL0 = &Vs[0][w * 512];
  short* VL1 = &Vs[0][2048 + w * 512];

#define STAGE(buf, kv0)                                                     \
  {                                                                         \
    GLOAD_LDS16(Kb + ((kv0) + kr0) * 64 + kc0, KL0 + (buf)*4096);           \
    GLOAD_LDS16(Kb + ((kv0) + kr1) * 64 + kc1, KL1 + (buf)*4096);           \
    GLOAD_LDS16(Vb + kr0 * 2048 + (kv0) + kc0, VL0 + (buf)*4096);           \
    GLOAD_LDS16(Vb + kr1 * 2048 + (kv0) + kc1, VL1 + (buf)*4096);           \
  }

  short* Pw = &P[w][0];
  const int bb = bh >> 3, hh = bh & 7;
  const f32x4 CINIT = {-16.f, -16.f, -16.f, -16.f};

  for (int ph = 0; ph < 2; ++ph) {
    const int jc = ph ? (31 - j) : j;
    const int qbase = jc * 64 + w * 16;
    const int ntiles = jc + 1;

    short8 qf0 = *(const short8*)&Qb[(qbase + c) * 64 + 8 * g];
    short8 qf1 = *(const short8*)&Qb[(qbase + c) * 64 + 8 * g + 32];

    f32x4 o[4];
    float psum[4];
#pragma unroll
    for (int nt = 0; nt < 4; nt++) o[nt] = f32x4{0.f, 0.f, 0.f, 0.f};
#pragma unroll
    for (int r = 0; r < 4; r++) psum[r] = 0.f;

    STAGE(0, 0);
    __syncthreads();

    int cur = 0;
    for (int it = 0; it < ntiles; ++it) {
      const int kv0 = it * 64;
      if (it + 1 < ntiles) STAGE(cur ^ 1, kv0 + 64);

      const short* Kt = &Ks[cur][0];
      const short* Vt = &Vs[cur][0];

      // QK^T from LDS (swizzle-read); C-init = -16 folds the softmax offset
      f32x4 sa[4];
#pragma unroll
      for (int nt = 0; nt < 4; nt++) {
        short8 kf0 = *(const short8*)&Kt[((nt * 16 + c) << 6) + ((g ^ (c & 7)) << 3)];
        short8 kf1 = *(const short8*)&Kt[((nt * 16 + c) << 6) + (((g + 4) ^ (c & 7)) << 3)];
        sa[nt] = mfma16(qf0, kf0, CINIT);
        sa[nt] = mfma16(qf1, kf1, sa[nt]);
      }

      // causal mask (only the diagonal tile for this wave's rows)
      if (kv0 + 64 > qbase) {
#pragma unroll
        for (int nt = 0; nt < 4; nt++) {
          int kv = kv0 + nt * 16 + c;
#pragma unroll
          for (int r = 0; r < 4; r++) {
            int qrow = qbase + 4 * g + r;
            if (kv > qrow) sa[nt][r] = -1e30f;
          }
        }
      }

      // p = exp2(s); partial row sums; pack to swizzled P (round-4 path)
#pragma unroll
      for (int nt = 0; nt < 4; nt++)
#pragma unroll
        for (int r = 0; r < 4; r++) {
          float pv = exp2f(sa[nt][r]);
          psum[r] += pv;
          int row = 4 * g + r;
          int col = nt * 16 + c;
          int off = (row << 6) + ((((col >> 3) ^ (row & 7)) << 3)) + (col & 7);
          *(__hip_bfloat16*)&Pw[off] = __float2bfloat16(pv);
        }

      // PV from LDS P and V (swizzle-read)
#pragma unroll
      for (int kvb = 0; kvb < 2; kvb++) {
        short8 pa = *(const short8*)&Pw[(c << 6) + (((kvb * 4 + g) ^ (c & 7)) << 3)];
#pragma unroll
        for (int nt = 0; nt < 4; nt++) {
          short8 vb = *(const short8*)&Vt[((nt * 16 + c) << 6) +
                                          (((kvb * 4 + g) ^ (c & 7)) << 3)];
          o[nt] = mfma16(pa, vb, o[nt]);
        }
      }

      __syncthreads();
      cur ^= 1;
    }

    // row-sum reduce over the 16 c-lanes in each g-group
#pragma unroll
    for (int off = 1; off < 16; off <<= 1)
#pragma unroll
      for (int r = 0; r < 4; r++) psum[r] += __shfl_xor(psum[r], off, 64);

    float inv[4];
#pragma unroll
    for (int r = 0; r < 4; r++) inv[r] = 1.0f / psum[r];
#pragma unroll
    for (int nt = 0; nt < 4; nt++)
#pragma unroll
      for (int r = 0; r < 4; r++) {
        int srow = qbase + 4 * g + r;
        ctx[(bb * S_ + srow) * 512 + hh * 64 + nt * 16 + c] =
            (short)f2bf(o[nt][r] * inv[r]);
      }
  }
#undef STAGE
}

// ---------------- launcher ----------------

extern "C" void kernel_launch(void* const* d_in, const int* in_sizes, int n_in,
                              void* d_out, int out_size, void* d_ws, size_t ws_size,
                              hipStream_t stream) {
  const float* x = (const float*)d_in[0];
  const float* Wqkv = (const float*)d_in[2];
  const float* bqkv = (const float*)d_in[3];
  const float* Wo = (const float*)d_in[4];
  const float* bo = (const float*)d_in[5];
  float* out = (float*)d_out;

  char* ws = (char*)d_ws;
  short* xb    = (short*)(ws + 0);
  short* wqkvt = (short*)(ws + 8388608);
  short* wot   = (short*)(ws + 9961472);
  short* Qw    = (short*)(ws + 10485760);
  short* Kw    = (short*)(ws + 18874368);
  short* VTw   = (short*)(ws + 27262976);
  short* ctx   = (short*)(ws + 35651584);

  k_cvt_bf16x8<<<2048, 256, 0, stream>>>(x, xb);
  k_cvt_transpose<<<3072, 256, 0, stream>>>(Wqkv, wqkvt, 1536);
  k_cvt_transpose<<<1024, 256, 0, stream>>>(Wo, wot, 512);

  dim3 g1(64, 12);
  k_gemm<0><<<g1, 256, 0, stream>>>(xb, wqkvt, bqkv, Qw, Kw, VTw, nullptr);

  k_attn<<<512, 256, 0, stream>>>(Qw, Kw, VTw, ctx);

  dim3 g3(64, 4);
  k_gemm<1><<<g3, 256, 0, stream>>>(ctx, wot, bo, nullptr, nullptr, nullptr, out);
}

// Round 7
// 102.006 us; speedup vs baseline: 1.9993x; 1.0314x over previous
//
#include <hip/hip_runtime.h>
#include <hip/hip_bf16.h>

#define S_ 2048
#define D_ 512
#define HD_ 64
#define HH_ 8
#define M_ 8192

typedef __attribute__((ext_vector_type(8))) short short8;
typedef __attribute__((ext_vector_type(4))) short short4v;
typedef __attribute__((ext_vector_type(4))) float f32x4;

__device__ __forceinline__ unsigned short f2bf(float f) {
  unsigned u = __builtin_bit_cast(unsigned, f);
  u += 0x7fffu + ((u >> 16) & 1u);
  return (unsigned short)(u >> 16);
}

__device__ __forceinline__ f32x4 mfma16(short8 a, short8 b, f32x4 c) {
  return __builtin_amdgcn_mfma_f32_16x16x32_bf16(a, b, c, 0, 0, 0);
}

#define GLOAD_LDS16(gp, lp)                                                        \
  __builtin_amdgcn_global_load_lds(                                                \
      (const __attribute__((address_space(1))) void*)(gp),                         \
      (__attribute__((address_space(3))) void*)(lp), 16, 0, 0)

// ---------------- converts ----------------

__global__ __launch_bounds__(256) void k_cvt_bf16x8(const float* __restrict__ x,
                                                    short* __restrict__ o) {
  int idx = blockIdx.x * 256 + threadIdx.x;
  const float4* p = (const float4*)x;
  float4 a = p[idx * 2];
  float4 b = p[idx * 2 + 1];
  short8 v;
  v[0] = (short)f2bf(a.x); v[1] = (short)f2bf(a.y);
  v[2] = (short)f2bf(a.z); v[3] = (short)f2bf(a.w);
  v[4] = (short)f2bf(b.x); v[5] = (short)f2bf(b.y);
  v[6] = (short)f2bf(b.z); v[7] = (short)f2bf(b.w);
  *(short8*)&o[idx * 8] = v;
}

__global__ __launch_bounds__(256) void k_cvt_transpose(const float* __restrict__ w,
                                                       short* __restrict__ wt,
                                                       int C) {
  int idx = blockIdx.x * 256 + threadIdx.x;
  int k = idx & 511;
  int n = idx >> 9;
  if (n < C) wt[n * 512 + k] = (short)f2bf(w[k * C + n]);
}

// ---------------- GEMM (128x128 tile, BK=32, 4 waves) ----------------
// MODE 0: qkv epilogue; Q pre-scaled by 0.125*log2e; K stored with 16B-chunk
// XOR swizzle (chunk' = chunk ^ (s&7)); V^T stored with column-chunk swizzle
// (chunk' = chunk ^ (hd&7) within each 64-col block). MODE 1: fp32 + bias.
template <int MODE>
__global__ __launch_bounds__(256) void k_gemm(const short* __restrict__ A,
                                              const short* __restrict__ Bt,
                                              const float* __restrict__ bias,
                                              short* __restrict__ Qo,
                                              short* __restrict__ Ko,
                                              short* __restrict__ VTo,
                                              float* __restrict__ Fo) {
  __shared__ short As[4096];
  __shared__ short Bs[4096];
  const int tid = threadIdx.x;
  const int w = tid >> 6, l = tid & 63, g = l >> 4, c = l & 15;
  const int bm = blockIdx.x * 128, bn = blockIdx.y * 128;
  const int wm = (w >> 1) * 64, wn = (w & 1) * 64;
  const int ch = w * 64 + l;
  const int ar = ch >> 2;
  const int ac = (ch & 3) * 8;
  f32x4 acc[4][4] = {};
  const short* Ap = A + (bm + ar) * 512 + ac;
  const short* Ap2 = Ap + 64 * 512;
  const short* Bp = Bt + (bn + ar) * 512 + ac;
  const short* Bp2 = Bp + 64 * 512;
  short* AsW = &As[w * 512];
  short* BsW = &Bs[w * 512];

  for (int k0 = 0; k0 < 512; k0 += 32) {
    __syncthreads();
    GLOAD_LDS16(Ap + k0, AsW);
    GLOAD_LDS16(Ap2 + k0, AsW + 2048);
    GLOAD_LDS16(Bp + k0, BsW);
    GLOAD_LDS16(Bp2 + k0, BsW + 2048);
    __syncthreads();
    short8 af[4], bfr[4];
#pragma unroll
    for (int mt = 0; mt < 4; mt++)
      af[mt] = *(const short8*)&As[(wm + mt * 16 + c) * 32 + 8 * g];
#pragma unroll
    for (int nt = 0; nt < 4; nt++)
      bfr[nt] = *(const short8*)&Bs[(wn + nt * 16 + c) * 32 + 8 * g];
#pragma unroll
    for (int mt = 0; mt < 4; mt++)
#pragma unroll
      for (int nt = 0; nt < 4; nt++)
        acc[mt][nt] = mfma16(af[mt], bfr[nt], acc[mt][nt]);
  }

  if (MODE == 0) {
    const float QS = 0.125f * 1.4426950408889634f;
#pragma unroll
    for (int nt = 0; nt < 4; nt++) {
      int n = bn + wn + nt * 16 + c;
      float bv = bias[n];
      int h = n / 192;
      int t = n - h * 192;
      int type = t >> 6;
      int hd = t & 63;
      float sc = (type == 0) ? QS : 1.0f;
#pragma unroll
      for (int mt = 0; mt < 4; mt++) {
        int m0 = bm + wm + mt * 16 + 4 * g;
        int b = m0 >> 11, s0 = m0 & 2047;
        int bh = b * 8 + h;
        if (type == 2) {
          int sw = (s0 & ~63) | (((((s0 >> 3) & 7) ^ (hd & 7)) << 3)) | (s0 & 7);
          short4v pk;
#pragma unroll
          for (int r = 0; r < 4; r++) pk[r] = (short)f2bf(acc[mt][nt][r] + bv);
          *(short4v*)&VTo[(bh * 64 + hd) * 2048 + sw] = pk;
        } else if (type == 1) {
#pragma unroll
          for (int r = 0; r < 4; r++) {
            int s = s0 + r;
            int hds = ((((hd >> 3) ^ (s & 7)) << 3)) | (hd & 7);
            Ko[(bh * 2048 + s) * 64 + hds] = (short)f2bf(acc[mt][nt][r] + bv);
          }
        } else {
#pragma unroll
          for (int r = 0; r < 4; r++)
            Qo[(bh * 2048 + s0 + r) * 64 + hd] = (short)f2bf((acc[mt][nt][r] + bv) * sc);
        }
      }
    }
  } else {
#pragma unroll
    for (int nt = 0; nt < 4; nt++) {
      int n = bn + wn + nt * 16 + c;
      float bv = bias[n];
#pragma unroll
      for (int mt = 0; mt < 4; mt++) {
        int m0 = bm + wm + mt * 16 + 4 * g;
#pragma unroll
        for (int r = 0; r < 4; r++) Fo[(m0 + r) * 512 + n] = acc[mt][nt][r] + bv;
      }
    }
  }
}

// ---------------- flash attention (high-occupancy, LDS-staged) ----------------
// 1024 blocks = 32 bh x 32 q-chunks (64 rows; 4 waves x 16 rows). Chunk j does
// j+1 kv-tiles; heavy chunks dispatched first (LPT). LDS 40KB -> 4 blocks/CU
// -> 4 waves/SIMD. KV double-buffered via global_load_lds; fixed-max softmax
// p = exp2(s-16) with -16 folded into MFMA C-init; P packed via 4-instr f2bf.
__global__ __launch_bounds__(256, 4) void k_attn(const short* __restrict__ Q,
                                                 const short* __restrict__ K,
                                                 const short* __restrict__ VT,
                                                 short* __restrict__ ctx) {
  __shared__ short Ks[2][4096];   // [64 kv][64 hd] swizzled
  __shared__ short Vs[2][4096];   // [64 hd][64 kv] swizzled
  __shared__ short P[4][1024];    // per-wave [16 q][64 kv] swizzled
  const int tid = threadIdx.x;
  const int w = tid >> 6, l = tid & 63, g = l >> 4, c = l & 15;

  const int x = blockIdx.x;
  const int bh = x & 31;
  const int jc = 31 - (x >> 5);    // 0..31, heaviest first
  const int qbase = jc * 64 + w * 16;
  const int ntiles = jc + 1;

  const short* Qb = Q + bh * S_ * HD_;
  const short* Kb = K + bh * S_ * HD_;
  const short* Vb = VT + bh * HD_ * S_;

  const int i0 = tid, i1 = tid + 256;
  const int kr0 = i0 >> 3, kc0 = (i0 & 7) * 8;
  const int kr1 = i1 >> 3, kc1 = (i1 & 7) * 8;
  short* KL0 = &Ks[0][w * 512];
  short* KL1 = &Ks[0][2048 + w * 512];
  short* VL0 = &Vs[0][w * 512];
  short* VL1 = &Vs[0][2048 + w * 512];

#define STAGE(buf, kv0)                                                     \
  {                                                                         \
    GLOAD_LDS16(Kb + ((kv0) + kr0) * 64 + kc0, KL0 + (buf)*4096);           \
    GLOAD_LDS16(Kb + ((kv0) + kr1) * 64 + kc1, KL1 + (buf)*4096);           \
    GLOAD_LDS16(Vb + kr0 * 2048 + (kv0) + kc0, VL0 + (buf)*4096);           \
    GLOAD_LDS16(Vb + kr1 * 2048 + (kv0) + kc1, VL1 + (buf)*4096);           \
  }

  short* Pw = &P[w][0];
  const int bb = bh >> 3, hh = bh & 7;
  const f32x4 CINIT = {-16.f, -16.f, -16.f, -16.f};

  short8 qf0 = *(const short8*)&Qb[(qbase + c) * 64 + 8 * g];
  short8 qf1 = *(const short8*)&Qb[(qbase + c) * 64 + 8 * g + 32];

  f32x4 o[4];
  float psum[4];
#pragma unroll
  for (int nt = 0; nt < 4; nt++) o[nt] = f32x4{0.f, 0.f, 0.f, 0.f};
#pragma unroll
  for (int r = 0; r < 4; r++) psum[r] = 0.f;

  STAGE(0, 0);
  __syncthreads();

  int cur = 0;
  for (int it = 0; it < ntiles; ++it) {
    const int kv0 = it * 64;
    if (it + 1 < ntiles) STAGE(cur ^ 1, kv0 + 64);

    const short* Kt = &Ks[cur][0];
    const short* Vt = &Vs[cur][0];

    // QK^T from LDS (swizzle-read); C-init = -16 folds the softmax offset
    f32x4 sa[4];
#pragma unroll
    for (int nt = 0; nt < 4; nt++) {
      short8 kf0 = *(const short8*)&Kt[((nt * 16 + c) << 6) + ((g ^ (c & 7)) << 3)];
      short8 kf1 = *(const short8*)&Kt[((nt * 16 + c) << 6) + (((g + 4) ^ (c & 7)) << 3)];
      sa[nt] = mfma16(qf0, kf0, CINIT);
      sa[nt] = mfma16(qf1, kf1, sa[nt]);
    }

    // causal mask (only the diagonal tile for this wave's rows)
    if (kv0 + 64 > qbase) {
#pragma unroll
      for (int nt = 0; nt < 4; nt++) {
        int kv = kv0 + nt * 16 + c;
#pragma unroll
        for (int r = 0; r < 4; r++) {
          int qrow = qbase + 4 * g + r;
          if (kv > qrow) sa[nt][r] = -1e30f;
        }
      }
    }

    // p = exp2(s); partial row sums; pack to swizzled P via f2bf (no NaN path)
#pragma unroll
    for (int nt = 0; nt < 4; nt++)
#pragma unroll
      for (int r = 0; r < 4; r++) {
        float pv = exp2f(sa[nt][r]);
        psum[r] += pv;
        int row = 4 * g + r;
        int col = nt * 16 + c;
        int off = (row << 6) + ((((col >> 3) ^ (row & 7)) << 3)) + (col & 7);
        Pw[off] = (short)f2bf(pv);
      }

    // PV from LDS P and V (swizzle-read)
#pragma unroll
    for (int kvb = 0; kvb < 2; kvb++) {
      short8 pa = *(const short8*)&Pw[(c << 6) + (((kvb * 4 + g) ^ (c & 7)) << 3)];
#pragma unroll
      for (int nt = 0; nt < 4; nt++) {
        short8 vb = *(const short8*)&Vt[((nt * 16 + c) << 6) +
                                        (((kvb * 4 + g) ^ (c & 7)) << 3)];
        o[nt] = mfma16(pa, vb, o[nt]);
      }
    }

    __syncthreads();
    cur ^= 1;
  }

  // row-sum reduce over the 16 c-lanes in each g-group
#pragma unroll
  for (int off = 1; off < 16; off <<= 1)
#pragma unroll
    for (int r = 0; r < 4; r++) psum[r] += __shfl_xor(psum[r], off, 64);

  float inv[4];
#pragma unroll
  for (int r = 0; r < 4; r++) inv[r] = 1.0f / psum[r];
#pragma unroll
  for (int nt = 0; nt < 4; nt++)
#pragma unroll
    for (int r = 0; r < 4; r++) {
      int srow = qbase + 4 * g + r;
      ctx[(bb * S_ + srow) * 512 + hh * 64 + nt * 16 + c] =
          (short)f2bf(o[nt][r] * inv[r]);
    }
#undef STAGE
}

// ---------------- launcher ----------------

extern "C" void kernel_launch(void* const* d_in, const int* in_sizes, int n_in,
                              void* d_out, int out_size, void* d_ws, size_t ws_size,
                              hipStream_t stream) {
  const float* x = (const float*)d_in[0];
  const float* Wqkv = (const float*)d_in[2];
  const float* bqkv = (const float*)d_in[3];
  const float* Wo = (const float*)d_in[4];
  const float* bo = (const float*)d_in[5];
  float* out = (float*)d_out;

  char* ws = (char*)d_ws;
  short* xb    = (short*)(ws + 0);
  short* wqkvt = (short*)(ws + 8388608);
  short* wot   = (short*)(ws + 9961472);
  short* Qw    = (short*)(ws + 10485760);
  short* Kw    = (short*)(ws + 18874368);
  short* VTw   = (short*)(ws + 27262976);
  short* ctx   = (short*)(ws + 35651584);

  k_cvt_bf16x8<<<2048, 256, 0, stream>>>(x, xb);
  k_cvt_transpose<<<3072, 256, 0, stream>>>(Wqkv, wqkvt, 1536);
  k_cvt_transpose<<<1024, 256, 0, stream>>>(Wo, wot, 512);

  dim3 g1(64, 12);
  k_gemm<0><<<g1, 256, 0, stream>>>(xb, wqkvt, bqkv, Qw, Kw, VTw, nullptr);

  k_attn<<<1024, 256, 0, stream>>>(Qw, Kw, VTw, ctx);

  dim3 g3(64, 4);
  k_gemm<1><<<g3, 256, 0, stream>>>(ctx, wot, bo, nullptr, nullptr, nullptr, out);
}